// Round 15
// baseline (823.423 us; speedup 1.0000x reference)
//
#include <hip/hip_runtime.h>
#include <math.h>

// ---------------- workspace layout (bytes) ----------------
#define WS_D     0ull                          // d f32: 4*65536*4 = 1 MB
#define WS_REF   1048576ull                    // refmap f32: 8 MB
#define WS_SPART 9437184ull                    // score partials float2 [2][4][65536] = 4 MB
#define WS_WSE   13631488ull                   // W_score_eff f64 [2][128][49] = 100352 B
#define WS_WRE   13731840ull                   // W_ref_eff f64 (legacy) = 50176 B
#define WS_WG    13782016ull                   // gather weights f32 [3136][26] = 326144 B
#define WS_TIDX  14108160ull                   // top_idx int [4][512] = 8192 B
#define WS_GATH  14116352ull                   // gathered f32 [4][512][26] = 212992 B
#define WS_TRIG  14329344ull                   // trig table f32 [2][6][64] = 3072 B
#define WS_CLIST 14332416ull                   // candidate idx int [4][2048] = 32768 B
#define WS_CNT   14365184ull                   // candidate count int [4] = 16 B
#define WS_PAIRS 14365200ull                   // (fgbits,idx) uint2 [4][2048] = 65536 B
#define WS_WRE32 14430736ull                   // W_ref_eff f32 [64][98] = 25088 B
#define WS_WSE32 14455824ull                   // W_score_eff f32 [128][98] = 50176 B
#define WS_END   14506000ull

typedef __attribute__((address_space(1))) const void cpn_gv;
typedef __attribute__((address_space(3))) void cpn_lv;

// ============================================================
// Kernel 1: composed weights (f64 + f32 SGPR-layout copies)
//           + gather-layout copies + trig table
// ============================================================
__global__ __launch_bounds__(256) void cpn_prep_kernel(
    const float* __restrict__ w_score_reduce, const float* __restrict__ w_score,
    const float* __restrict__ w_loc, const float* __restrict__ w_fourier,
    const float* __restrict__ w_ref_reduce, const float* __restrict__ w_ref,
    double* __restrict__ wse, double* __restrict__ wre, float* __restrict__ wg,
    float* __restrict__ trig, float* __restrict__ wre32, float* __restrict__ wse32)
{
    int i = blockIdx.x * 256 + threadIdx.x;
    if (i < 12544) {                    // wse f64 [o][c][49]
        int o = i / 6272;
        int rem = i % 6272;
        int c = rem / 49, r = rem % 49;
        double a = 0.0;
        for (int m = 0; m < 64; ++m)
            a += (double)w_score[(o*64 + m)*49 + r] * (double)w_score_reduce[m*128 + c];
        wse[i] = a;
    } else if (i < 12544 + 6272) {      // wre f64 (legacy)
        int t = i - 12544;
        int o = t / 3136;
        int rem = t % 3136;
        int c = rem / 49, r = rem % 49;
        double a = 0.0;
        for (int m = 0; m < 32; ++m)
            a += (double)w_ref[(o*32 + m)*49 + r] * (double)w_ref_reduce[m*64 + c];
        wre[t] = a;
    } else if (i < 12544 + 6272 + 81536) { // wg [3136][26]
        int t = i - 18816;
        int tap = t / 26, o = t % 26;
        wg[t] = (o < 2) ? w_loc[o*3136 + tap] : w_fourier[(o - 2)*3136 + tap];
    } else if (i < 100352 + 768) {      // trig table, bit-identical f32 chain
        int t = i - 100352;             // [cs][k][s]
        int cs = t / 384;
        int k = (t % 384) / 64, s = t % 64;
        const float TWO_PI_F = (float)6.283185307179586;
        float a1 = TWO_PI_F * (float)(k + 1);
        float tf = (float)s * 0.015625f;
        float ang = a1 * tf;
        double av = (double)ang;
        trig[t] = (cs == 0) ? (float)cos(av) : (float)sin(av);
    } else if (i < 101120 + 6272) {     // wre32: [c][ky][2*kx+o] f32
        int t = i - 101120;
        int c = t / 98, r98 = t % 98;
        int ky = r98 / 14, q = r98 % 14;
        int kx = q >> 1, o = q & 1;
        int rr = ky*7 + kx;
        double a = 0.0;
        for (int m = 0; m < 32; ++m)
            a += (double)w_ref[(o*32 + m)*49 + rr] * (double)w_ref_reduce[m*64 + c];
        wre32[t] = (float)a;
    } else if (i < 107392 + 12544) {    // wse32: [c][ky][2*kx+o] f32, c 0..127
        int t = i - 107392;
        int c = t / 98, r98 = t % 98;
        int ky = r98 / 14, q = r98 % 14;
        int kx = q >> 1, o = q & 1;
        int rr = ky*7 + kx;
        double a = 0.0;
        for (int m = 0; m < 64; ++m)
            a += (double)w_score[(o*64 + m)*49 + rr] * (double)w_score_reduce[m*128 + c];
        wse32[t] = (float)a;
    }
}

// ============================================================
// Kernel 2: score conv f32 ranking pass, DMA staging.
//   512 thr = 2 K-halves (32 ch each). Patch [h][buf][380] float4,
//   global_load_lds width 16, double-buffered, 1 barrier/channel.
//   Staged values + FMA order identical to r10 -> same partial bits.
// ============================================================
__global__ __launch_bounds__(512) void cpn_score_dense_kernel(
    const float* __restrict__ cf, const float* __restrict__ esf,
    const float* __restrict__ wse32, float2* __restrict__ partial)
{
    __shared__ __align__(16) float4 patch[2][2][380];   // 24320 B
    const int tid  = threadIdx.x;
    const int t2   = tid & 255;
    const int h    = tid >> 8;            // wave-uniform K-split half
    const int wv   = t2 >> 6;             // wave within half (0..3)
    const int b    = blockIdx.z >> 1;
    const int srch = blockIdx.z & 1;
    const float* src = srch ? esf : cf;
    const float* sbase = src + ((size_t)(b*64 + h*32) << 16);
    const int row0 = blockIdx.y * 32;
    const int col0 = blockIdx.x * 32;
    const int ty   = t2 >> 3;
    const int txg  = t2 & 7;
    const int cbase = srch*64 + h*32;

    // slots: s = k*256 + t2; row = s/10 (0..37), f = s%10 (40 floats/row)
    long st_off[2];
    bool st_ok[2];
    #pragma unroll
    for (int k = 0; k < 2; ++k) {
        int i = k*256 + t2;
        int r = i / 10, f = i % 10;
        int gy = row0 - 3 + r, gx = col0 - 4 + 4*f;
        st_ok[k] = (i < 380) && ((unsigned)gy < 256u) && ((unsigned)gx < 253u);
        st_off[k] = (long)gy * 256 + gx;
    }

    float4 z4 = {0.f,0.f,0.f,0.f};
    for (int i = tid; i < 2*2*380; i += 512) (&patch[0][0][0])[i] = z4;
    __syncthreads();

    #pragma unroll
    for (int k = 0; k < 2; ++k)
        if (st_ok[k])
            __builtin_amdgcn_global_load_lds(
                (cpn_gv*)(sbase + st_off[k]),
                (cpn_lv*)&patch[h][0][k*256 + wv*64], 16, 0, 0);

    float acc0[4] = {0.f,0.f,0.f,0.f};
    float acc1[4] = {0.f,0.f,0.f,0.f};

    for (int c = 0; c < 32; ++c) {
        __syncthreads();                  // drains DMA(c); buf[(c+1)&1] free
        if (c + 1 < 32) {
            const float* sp = sbase + ((size_t)(c+1) << 16);
            #pragma unroll
            for (int k = 0; k < 2; ++k)
                if (st_ok[k])
                    __builtin_amdgcn_global_load_lds(
                        (cpn_gv*)(sp + st_off[k]),
                        (cpn_lv*)&patch[h][(c+1)&1][k*256 + wv*64], 16, 0, 0);
        }
        int cg = __builtin_amdgcn_readfirstlane(cbase + c);
        const float* wc = wse32 + cg*98;         // uniform -> scalar loads
        const float4* pb = &patch[h][c & 1][0];
        #pragma unroll
        for (int ky = 0; ky < 7; ++ky) {
            int row = ty + ky;
            float4 A  = pb[row*10 + txg + 0];
            float4 B2 = pb[row*10 + txg + 1];
            float4 C2 = pb[row*10 + txg + 2];
            float rv[12] = {A.x,A.y,A.z,A.w,B2.x,B2.y,B2.z,B2.w,C2.x,C2.y,C2.z,C2.w};
            const float* wp = wc + ky*14;
            float wv14[14];
            #pragma unroll
            for (int q = 0; q < 14; ++q) wv14[q] = wp[q];
            #pragma unroll
            for (int kx = 0; kx < 7; ++kx) {
                float w0 = wv14[2*kx], w1 = wv14[2*kx+1];
                #pragma unroll
                for (int p = 0; p < 4; ++p) {
                    float v = rv[p + kx + 1];
                    acc0[p] = fmaf(w0, v, acc0[p]);
                    acc1[p] = fmaf(w1, v, acc1[p]);
                }
            }
        }
    }
    __syncthreads();

    float* cmb = reinterpret_cast<float*>(&patch[0][0][0]);   // 8 KB alias
    if (h == 1) {
        #pragma unroll
        for (int p = 0; p < 4; ++p) { cmb[t2*8 + p] = acc0[p]; cmb[t2*8 + 4 + p] = acc1[p]; }
    }
    __syncthreads();
    if (h == 0) {
        int y = row0 + ty;
        #pragma unroll
        for (int p = 0; p < 4; ++p) {
            float s0 = acc0[p] + cmb[t2*8 + p];
            float s1 = acc1[p] + cmb[t2*8 + 4 + p];
            int x = col0 + txg*4 + p;
            float2 v; v.x = s0; v.y = s1;
            partial[(size_t)(srch*4 + b)*65536 + y*256 + x] = v;
        }
    }
}

// ============================================================
// Kernel 3: d = l1 - l0 (ranking surrogate)
// ============================================================
__global__ __launch_bounds__(256) void cpn_dcomb_kernel(
    const float2* __restrict__ partial, float* __restrict__ d)
{
    int i = blockIdx.x * 256 + threadIdx.x;
    int b = i >> 16, px = i & 65535;
    float2 p0 = partial[(size_t)b*65536 + px];
    float2 p1 = partial[(size_t)(4 + b)*65536 + px];
    float l0 = p0.x + p1.x;
    float l1 = p0.y + p1.y;
    d[i] = l1 - l0;
}

// ============================================================
// Kernel 4: refinement conv f32, DMA staging. 512 thr = 2 K-halves.
//   Patch [h][buf][684] float4 (38 rows x 18 f4), global_load_lds,
//   double-buffered, 1 barrier/channel. FMA order == r10 -> refmap
//   bit-identical.
// ============================================================
__global__ __launch_bounds__(512) void cpn_ref_conv_kernel(
    const float* __restrict__ rff, const float* __restrict__ erf,
    const float* __restrict__ wre32, const float* __restrict__ b_ref,
    float* __restrict__ refmap)
{
    __shared__ __align__(16) float4 patch[2][2][684];   // 43776 B
    const int tid = threadIdx.x;
    const int t2  = tid & 255;
    const int h   = tid >> 8;             // wave-uniform
    const int wv  = t2 >> 6;              // wave within half (0..3)
    const int b   = blockIdx.z;
    const int row0 = blockIdx.y * 32;
    const int col0 = blockIdx.x * 64;
    const int tyg = t2 & 31;              // output row
    const int txg = t2 >> 5;              // 8 px each
    const float* sbase = (h ? erf : rff) + ((size_t)(b*32) << 18);

    // slots: s = k*256 + t2; row = s/18 (0..37), f = s%18 (72 floats/row)
    long st_off[3];
    bool st_ok[3];
    #pragma unroll
    for (int k = 0; k < 3; ++k) {
        int i = k*256 + t2;
        int r = i / 18, f = i % 18;
        int gy = row0 - 3 + r, gx = col0 - 4 + 4*f;
        st_ok[k] = (i < 684) && ((unsigned)gy < 512u) && ((unsigned)gx < 509u);
        st_off[k] = (long)gy * 512 + gx;
    }

    float4 z4 = {0.f,0.f,0.f,0.f};
    for (int i = tid; i < 2*2*684; i += 512) (&patch[0][0][0])[i] = z4;
    __syncthreads();

    #pragma unroll
    for (int k = 0; k < 3; ++k)
        if (st_ok[k])
            __builtin_amdgcn_global_load_lds(
                (cpn_gv*)(sbase + st_off[k]),
                (cpn_lv*)&patch[h][0][k*256 + wv*64], 16, 0, 0);

    float acc0[8] = {0,0,0,0,0,0,0,0};
    float acc1[8] = {0,0,0,0,0,0,0,0};

    for (int c = 0; c < 32; ++c) {
        __syncthreads();                  // drains DMA(c); buf[(c+1)&1] free
        if (c + 1 < 32) {
            const float* sp = sbase + ((size_t)(c+1) << 18);
            #pragma unroll
            for (int k = 0; k < 3; ++k)
                if (st_ok[k])
                    __builtin_amdgcn_global_load_lds(
                        (cpn_gv*)(sp + st_off[k]),
                        (cpn_lv*)&patch[h][(c+1)&1][k*256 + wv*64], 16, 0, 0);
        }
        int cg = __builtin_amdgcn_readfirstlane(h*32 + c);
        const float* wc = wre32 + cg*98;       // uniform -> scalar loads
        const float4* pb = &patch[h][c & 1][0];
        #pragma unroll
        for (int pr = 0; pr < 7; ++pr) {       // pr == ky
            int row = tyg + pr;
            float4 A  = pb[row*18 + 2*txg + 0];
            float4 B2 = pb[row*18 + 2*txg + 1];
            float4 C2 = pb[row*18 + 2*txg + 2];
            float4 D2 = pb[row*18 + 2*txg + 3];
            float rv[16] = {A.x,A.y,A.z,A.w,B2.x,B2.y,B2.z,B2.w,
                            C2.x,C2.y,C2.z,C2.w,D2.x,D2.y,D2.z,D2.w};
            const float* wp = wc + pr*14;
            float wv14[14];
            #pragma unroll
            for (int q = 0; q < 14; ++q) wv14[q] = wp[q];
            #pragma unroll
            for (int kx = 0; kx < 7; ++kx) {
                float w0 = wv14[2*kx], w1 = wv14[2*kx+1];
                #pragma unroll
                for (int p = 0; p < 8; ++p) {
                    float v = rv[p + kx + 1];
                    acc0[p] = fmaf(w0, v, acc0[p]);
                    acc1[p] = fmaf(w1, v, acc1[p]);
                }
            }
        }
    }
    __syncthreads();

    float* cmb = reinterpret_cast<float*>(&patch[0][0][0]);   // 16 KB alias
    if (h == 1) {
        #pragma unroll
        for (int p = 0; p < 8; ++p) { cmb[t2*16 + p] = acc0[p]; cmb[t2*16 + 8 + p] = acc1[p]; }
    }
    __syncthreads();
    if (h == 0) {
        float br0 = b_ref[0], br1 = b_ref[1];
        int y = row0 + tyg;
        int x0 = col0 + txg*8;
        #pragma unroll
        for (int p = 0; p < 8; ++p) {
            float s0 = acc0[p] + cmb[t2*16 + p];
            float s1 = acc1[p] + cmb[t2*16 + 8 + p];
            refmap[((size_t)(b*2 + 0)*512 + y)*512 + x0 + p] = tanhf(s0 + br0) * 3.0f;
            refmap[((size_t)(b*2 + 1)*512 + y)*512 + x0 + p] = tanhf(s1 + br1) * 3.0f;
        }
    }
}

// ============================================================
// Kernel 5: candidate select (radix 512th d, margin 0.0625) [r10]
// ============================================================
__device__ __forceinline__ void cpn_find_bucket(
    unsigned int* hist, unsigned int* seg, int nb, int target, int tid,
    int* s_bsel, int* s_cnt)
{
    int nseg = nb / 32;
    for (int t = tid; t < nseg; t += 1024) {
        unsigned int s = 0;
        for (int q = 0; q < 32; ++q) s += hist[t*32 + q];
        seg[t] = s;
    }
    __syncthreads();
    if (tid == 0) {
        int cum = 0, sg = 0;
        for (int jj = nseg - 1; jj >= 0; --jj) {
            int c = (int)seg[jj];
            if (cum + c >= target) { sg = jj; break; }
            cum += c;
        }
        int bs = sg*32;
        for (int jj = sg*32 + 31; jj >= sg*32; --jj) {
            int c = (int)hist[jj];
            if (cum + c >= target) { bs = jj; break; }
            cum += c;
        }
        *s_bsel = bs; *s_cnt = cum;
    }
    __syncthreads();
}

__device__ __forceinline__ unsigned int cpn_fkey(float v) {
    unsigned int u = __float_as_uint(v);
    return (u & 0x80000000u) ? ~u : (u | 0x80000000u);
}

__global__ __launch_bounds__(1024) void cpn_select_kernel(
    const float* __restrict__ d, int* __restrict__ clist, int* __restrict__ cnt)
{
    const int b = blockIdx.x;
    const int tid = threadIdx.x;
    const float* f = d + (size_t)b * 65536;

    __shared__ unsigned int hist[2048];
    __shared__ unsigned int seg[64];
    __shared__ int s_b, s_c, s_n;

    const int bitsA[3]  = {11,11,10};
    const int shiftA[3] = {21,10,0};

    unsigned int prefix = 0;
    int target = 512;
    for (int pass = 0; pass < 3; ++pass) {
        int sh = shiftA[pass], nb = 1 << bitsA[pass];
        for (int i = tid; i < 2048; i += 1024) hist[i] = 0;
        __syncthreads();
        if (pass == 0) {
            for (int i = tid; i < 65536; i += 1024) {
                unsigned int k = cpn_fkey(f[i]);
                atomicAdd(&hist[k >> 21], 1u);
            }
        } else {
            int hs = sh + bitsA[pass];
            for (int i = tid; i < 65536; i += 1024) {
                unsigned int k = cpn_fkey(f[i]);
                if ((k >> hs) == prefix)
                    atomicAdd(&hist[(k >> sh) & (nb-1)], 1u);
            }
        }
        __syncthreads();
        cpn_find_bucket(hist, seg, nb, target, tid, &s_b, &s_c);
        prefix = (prefix << bitsA[pass]) | (unsigned)s_b;
        target -= s_c;
    }
    float T = (prefix & 0x80000000u) ? __uint_as_float(prefix & 0x7FFFFFFFu)
                                     : __uint_as_float(~prefix);
    float tval = T - 0.0625f;

    if (tid == 0) s_n = 0;
    __syncthreads();
    for (int i = tid; i < 65536; i += 1024) {
        if (f[i] >= tval) {
            int q = atomicAdd(&s_n, 1);
            if (q < 2048) clist[b*2048 + q] = i;
        }
    }
    __syncthreads();
    if (tid == 0) cnt[b] = (s_n > 2048) ? 2048 : s_n;
}

// ============================================================
// Kernel 6: exact f64 logits at candidates + proven f32 fg chain
// ============================================================
__global__ __launch_bounds__(256) void cpn_recompute_kernel(
    const float* __restrict__ cf, const float* __restrict__ esf,
    const double* __restrict__ wse, const float* __restrict__ b_score,
    const int* __restrict__ clist, const int* __restrict__ cnt,
    uint2* __restrict__ pairs)
{
    const int b = blockIdx.y, q = blockIdx.x, tid = threadIdx.x;
    const int n = cnt[b];
    if (q >= n) {
        if (tid == 0) { uint2 pd; pd.x = 0u; pd.y = 0x7FFFFFFFu; pairs[b*2048 + q] = pd; }
        return;
    }
    const int idx = clist[b*2048 + q];
    const int gy = idx >> 8, gx = idx & 255;

    double L0 = 0.0, L1 = 0.0;
    for (int t = tid; t < 6272; t += 256) {
        int c = t / 49, r = t % 49, ky = r / 7, kx = r % 7;
        int y = gy + ky - 3, x = gx + kx - 3;
        float v = 0.f;
        if ((unsigned)y < 256u && (unsigned)x < 256u) {
            const float* src = (c < 64) ? cf : esf;
            v = src[((size_t)(b*64 + (c & 63)) << 16) + y*256 + x];
        }
        double dv = (double)v;
        L0 = fma(dv, wse[c*49 + r], L0);
        L1 = fma(dv, wse[6272 + c*49 + r], L1);
    }
    #pragma unroll
    for (int off = 32; off; off >>= 1) {
        L0 += __shfl_down(L0, off, 64);
        L1 += __shfl_down(L1, off, 64);
    }
    __shared__ double red[4][2];
    int w = tid >> 6, lane = tid & 63;
    if (lane == 0) { red[w][0] = L0; red[w][1] = L1; }
    __syncthreads();
    if (tid == 0) {
        double S0 = red[0][0] + red[1][0] + red[2][0] + red[3][0];
        double S1 = red[0][1] + red[1][1] + red[2][1] + red[3][1];
        float l0f = (float)(S0 + (double)b_score[0]);
        float l1f = (float)(S1 + (double)b_score[1]);
        float m  = fmaxf(l0f, l1f);
        float e0 = (float)exp((double)(l0f - m));
        float e1 = (float)exp((double)(l1f - m));
        float s  = e0 + e1;
        float lg = (float)log((double)s);
        float ls1 = (l1f - m) - lg;
        float fgv = (float)exp((double)ls1);
        uint2 pr; pr.x = __float_as_uint(fgv); pr.y = (unsigned)idx;
        pairs[b*2048 + q] = pr;
    }
}

// ============================================================
// Kernel 7: per-batch bitonic sort of 2048 (fgbits desc, idx asc)
// ============================================================
__global__ __launch_bounds__(1024) void cpn_sortk_kernel(
    const uint2* __restrict__ pairs, int* __restrict__ tidx,
    float* __restrict__ tscores)
{
    const int b = blockIdx.x;
    const int tid = threadIdx.x;
    __shared__ unsigned int key[2048];
    __shared__ int sidx[2048];

    for (int q = tid; q < 2048; q += 1024) {
        uint2 pr = pairs[b*2048 + q];
        key[q] = pr.x; sidx[q] = (int)pr.y;
    }
    __syncthreads();
    for (int kk = 2; kk <= 2048; kk <<= 1)
        for (int jj = kk >> 1; jj > 0; jj >>= 1) {
            for (int i = tid; i < 2048; i += 1024) {
                int ixj = i ^ jj;
                if (ixj > i) {
                    unsigned int ka = key[i], kc = key[ixj];
                    int ia = sidx[i], ic = sidx[ixj];
                    bool up = ((i & kk) == 0);
                    bool aBefore = (ka > kc) || (ka == kc && ia < ic);
                    if (up ? !aBefore : aBefore) {
                        key[i] = kc; key[ixj] = ka;
                        sidx[i] = ic; sidx[ixj] = ia;
                    }
                }
            }
            __syncthreads();
        }
    for (int q = tid; q < 512; q += 1024) {
        tscores[b*512 + q] = __uint_as_float(key[q]);
        tidx[b*512 + q] = sidx[q];
    }
}

// ============================================================
// Kernel 8: gathered 7x7x64 conv at top-k pts; f64 accum -> f32 [r10]
// ============================================================
__global__ __launch_bounds__(256) void cpn_gather_conv_kernel(
    const float* __restrict__ cf, const float* __restrict__ wg,
    const float* __restrict__ b_loc, const float* __restrict__ b_fourier,
    const int* __restrict__ tidx, float* __restrict__ gath)
{
    const int b = blockIdx.y, p = blockIdx.x, tid = threadIdx.x;
    const int idx = tidx[b*512 + p];
    const int gy = idx >> 8, gx = idx & 255;

    double part[26];
    #pragma unroll
    for (int o = 0; o < 26; ++o) part[o] = 0.0;

    for (int t = tid; t < 3136; t += 256) {
        int c = t / 49, rr = t % 49, ky = rr / 7, kx = rr % 7;
        int y = gy + ky - 3, x = gx + kx - 3;
        float v = 0.f;
        if ((unsigned)y < 256u && (unsigned)x < 256u)
            v = cf[((size_t)(b*64 + c)*256 + y)*256 + x];
        const float* wr = wg + t*26;
        double dv = (double)v;
        #pragma unroll
        for (int o = 0; o < 26; ++o) part[o] = fma(dv, (double)wr[o], part[o]);
    }
    #pragma unroll
    for (int o = 0; o < 26; ++o)
        for (int off = 32; off; off >>= 1) part[o] += __shfl_down(part[o], off, 64);

    __shared__ double red[4][26];
    int w = tid >> 6, lane = tid & 63;
    if (lane == 0) {
        #pragma unroll
        for (int o = 0; o < 26; ++o) red[w][o] = part[o];
    }
    __syncthreads();
    if (tid < 26) {
        double s = red[0][tid] + red[1][tid] + red[2][tid] + red[3][tid];
        s += (tid < 2) ? (double)b_loc[tid] : (double)b_fourier[tid - 2];
        gath[((size_t)b*512 + p)*26 + tid] = (float)s;
    }
}

// ============================================================
// Kernel 9: fourier synthesis + 4 refinement iters + boxes [r10]
// ============================================================
__global__ __launch_bounds__(64) void cpn_contour_kernel(
    const float* __restrict__ gath, const int* __restrict__ tidx,
    const float* __restrict__ refmap, const float* __restrict__ trig,
    float* __restrict__ out_contour, float* __restrict__ out_boxes)
{
    const int bp = blockIdx.x;
    const int b = bp >> 9;
    const int s = threadIdx.x;
    const float* g = gath + (size_t)bp * 26;
    const int idx = tidx[bp];
    const int gy = idx >> 8, gx = idx & 255;

    float cx = ((float)gx + g[0]) * 2.0f;
    float cy = ((float)gy + g[1]) * 2.0f;

    float sxc = 0.f, sxs = 0.f, syc = 0.f, sys = 0.f;
    #pragma unroll
    for (int k = 0; k < 6; ++k) {
        float cs = trig[k*64 + s];
        float sn = trig[384 + k*64 + s];
        float t0 = g[2 + k*4 + 0] * cs; asm volatile("" : "+v"(t0)); sxc += t0;
        float t1 = g[2 + k*4 + 1] * sn; asm volatile("" : "+v"(t1)); sxs += t1;
        float t2 = g[2 + k*4 + 2] * cs; asm volatile("" : "+v"(t2)); syc += t2;
        float t3 = g[2 + k*4 + 3] * sn; asm volatile("" : "+v"(t3)); sys += t3;
    }
    float px = sxc + sxs;
    float py = syc + sys;
    float x = px * 2.0f; asm volatile("" : "+v"(x)); x += cx;
    float y = py * 2.0f; asm volatile("" : "+v"(y)); y += cy;

    const float* r0 = refmap + (size_t)b * 2 * 262144;
    const float* r1 = r0 + 262144;
    #pragma unroll
    for (int it = 0; it < 4; ++it) {
        float xr = rintf(x); xr = fminf(fmaxf(xr, 0.f), 511.f);
        float yr = rintf(y); yr = fminf(fmaxf(yr, 0.f), 511.f);
        int xi = (int)xr, yi = (int)yr;
        x += r0[yi*512 + xi];
        y += r1[yi*512 + xi];
    }

    out_contour[((size_t)bp*64 + s)*2 + 0] = x;
    out_contour[((size_t)bp*64 + s)*2 + 1] = y;

    float mnx = x, mxx = x, mny = y, mxy = y;
    #pragma unroll
    for (int off = 32; off; off >>= 1) {
        mnx = fminf(mnx, __shfl_xor(mnx, off, 64));
        mny = fminf(mny, __shfl_xor(mny, off, 64));
        mxx = fmaxf(mxx, __shfl_xor(mxx, off, 64));
        mxy = fmaxf(mxy, __shfl_xor(mxy, off, 64));
    }
    if (s == 0) {
        out_boxes[bp*4 + 0] = mnx;
        out_boxes[bp*4 + 1] = mny;
        out_boxes[bp*4 + 2] = mxx;
        out_boxes[bp*4 + 3] = mxy;
    }
}

// ============================================================
// Kernel 10: sequential NMS, literal f32 op order [r10]
// ============================================================
__global__ __launch_bounds__(512) void cpn_nms_kernel(
    const float* __restrict__ boxes, const float* __restrict__ scores,
    float* __restrict__ keep_out)
{
    const int b = blockIdx.x;
    const int j = threadIdx.x;
    __shared__ float X1[512], Y1[512], X2[512], Y2[512], AR[512];
    __shared__ int keep[512];

    const float* bb = boxes + b*512*4;
    float x1 = bb[j*4+0], y1 = bb[j*4+1], x2 = bb[j*4+2], y2 = bb[j*4+3];
    float aj = fmaxf(x2 - x1, 0.f) * fmaxf(y2 - y1, 0.f);
    X1[j] = x1; Y1[j] = y1; X2[j] = x2; Y2[j] = y2; AR[j] = aj;
    keep[j] = (scores[b*512 + j] > 0.5f) ? 1 : 0;
    __syncthreads();

    for (int i = 0; i < 512; ++i) {
        if (keep[i] && j > i) {
            float ix1 = fmaxf(x1, X1[i]);
            float iy1 = fmaxf(y1, Y1[i]);
            float ix2 = fminf(x2, X2[i]);
            float iy2 = fminf(y2, Y2[i]);
            float inter = fmaxf(ix2 - ix1, 0.f) * fmaxf(iy2 - iy1, 0.f);
            float uni = (aj + AR[i]) - inter;
            float iou = inter / fmaxf(uni, 1e-8f);
            if (iou > 0.2f) keep[j] = 0;
        }
        __syncthreads();
    }
    keep_out[b*512 + j] = keep[j] ? 1.0f : 0.0f;
}

// ============================================================
extern "C" void kernel_launch(void* const* d_in, const int* in_sizes, int n_in,
                              void* d_out, int out_size, void* d_ws, size_t ws_size,
                              hipStream_t stream)
{
    if (ws_size < WS_END) return;

    const float* cf   = (const float*)d_in[0];
    const float* esf  = (const float*)d_in[1];
    const float* rff  = (const float*)d_in[2];
    const float* erf  = (const float*)d_in[3];
    const float* w_sr = (const float*)d_in[4];
    const float* w_s  = (const float*)d_in[5];
    const float* b_s  = (const float*)d_in[6];
    const float* w_l  = (const float*)d_in[7];
    const float* b_l  = (const float*)d_in[8];
    const float* w_f  = (const float*)d_in[9];
    const float* b_f  = (const float*)d_in[10];
    const float* w_rr = (const float*)d_in[11];
    const float* w_r  = (const float*)d_in[12];
    const float* b_r  = (const float*)d_in[13];

    char* ws = (char*)d_ws;
    float*  dbuf = (float*)(ws + WS_D);
    float*  refm = (float*)(ws + WS_REF);
    float2* spart = (float2*)(ws + WS_SPART);
    double* wse  = (double*)(ws + WS_WSE);
    double* wre  = (double*)(ws + WS_WRE);
    float*  wg   = (float*)(ws + WS_WG);
    int*    tidx = (int*)(ws + WS_TIDX);
    float*  gath = (float*)(ws + WS_GATH);
    float*  trig = (float*)(ws + WS_TRIG);
    int*    clist = (int*)(ws + WS_CLIST);
    int*    cnt  = (int*)(ws + WS_CNT);
    uint2*  pairs = (uint2*)(ws + WS_PAIRS);
    float*  wre32 = (float*)(ws + WS_WRE32);
    float*  wse32 = (float*)(ws + WS_WSE32);

    float* out_contour = (float*)d_out;                  // 4*512*64*2
    float* out_scores  = out_contour + 262144;           // 4*512
    float* out_keep    = out_scores + 2048;              // 4*512
    float* out_boxes   = out_keep + 2048;                // 4*512*4

    cpn_prep_kernel<<<dim3(469), dim3(256), 0, stream>>>(
        w_sr, w_s, w_l, w_f, w_rr, w_r, wse, wre, wg, trig, wre32, wse32);
    cpn_score_dense_kernel<<<dim3(8, 8, 8), dim3(512), 0, stream>>>(
        cf, esf, wse32, spart);
    cpn_ref_conv_kernel<<<dim3(8, 16, 4), dim3(512), 0, stream>>>(
        rff, erf, wre32, b_r, refm);
    cpn_dcomb_kernel<<<dim3(1024), dim3(256), 0, stream>>>(spart, dbuf);
    cpn_select_kernel<<<dim3(4), dim3(1024), 0, stream>>>(dbuf, clist, cnt);
    cpn_recompute_kernel<<<dim3(2048, 4), dim3(256), 0, stream>>>(
        cf, esf, wse, b_s, clist, cnt, pairs);
    cpn_sortk_kernel<<<dim3(4), dim3(1024), 0, stream>>>(pairs, tidx, out_scores);
    cpn_gather_conv_kernel<<<dim3(512, 4), dim3(256), 0, stream>>>(
        cf, wg, b_l, b_f, tidx, gath);
    cpn_contour_kernel<<<dim3(2048), dim3(64), 0, stream>>>(
        gath, tidx, refm, trig, out_contour, out_boxes);
    cpn_nms_kernel<<<dim3(4), dim3(512), 0, stream>>>(
        out_boxes, out_scores, out_keep);
}

// Round 16
// 665.811 us; speedup vs baseline: 1.2367x; 1.2367x over previous
//
#include <hip/hip_runtime.h>
#include <math.h>

// ---------------- workspace layout (bytes) ----------------
#define WS_D     0ull                          // d f32: 4*65536*4 = 1 MB
#define WS_REF   1048576ull                    // refmap f32: 8 MB
#define WS_SPART 9437184ull                    // score partials float2 [2][4][65536] = 4 MB
#define WS_WSE   13631488ull                   // W_score_eff f64 [2][128][49] = 100352 B
#define WS_WRE   13731840ull                   // W_ref_eff f64 (legacy) = 50176 B
#define WS_WG    13782016ull                   // gather weights f32 [3136][26] = 326144 B
#define WS_TIDX  14108160ull                   // top_idx int [4][512] = 8192 B
#define WS_GATH  14116352ull                   // (unused, kept for layout)
#define WS_TRIG  14329344ull                   // trig table f32 [2][6][64] = 3072 B
#define WS_CLIST 14332416ull                   // candidate idx int [4][2048] = 32768 B
#define WS_CNT   14365184ull                   // candidate count int [4] = 16 B
#define WS_PAIRS 14365200ull                   // (fgbits,idx) uint2 [4][2048] = 65536 B
#define WS_WRE32 14430736ull                   // W_ref_eff f32 [64][98] = 25088 B
#define WS_WSE32 14455824ull                   // W_score_eff f32 [128][98] = 50176 B
#define WS_END   14506000ull

// ============================================================
// Kernel 1: composed weights (f64 + f32 SGPR-layout copies)
//           + gather-layout copies + trig table
// ============================================================
__global__ __launch_bounds__(256) void cpn_prep_kernel(
    const float* __restrict__ w_score_reduce, const float* __restrict__ w_score,
    const float* __restrict__ w_loc, const float* __restrict__ w_fourier,
    const float* __restrict__ w_ref_reduce, const float* __restrict__ w_ref,
    double* __restrict__ wse, double* __restrict__ wre, float* __restrict__ wg,
    float* __restrict__ trig, float* __restrict__ wre32, float* __restrict__ wse32)
{
    int i = blockIdx.x * 256 + threadIdx.x;
    if (i < 12544) {                    // wse f64 [o][c][49]
        int o = i / 6272;
        int rem = i % 6272;
        int c = rem / 49, r = rem % 49;
        double a = 0.0;
        for (int m = 0; m < 64; ++m)
            a += (double)w_score[(o*64 + m)*49 + r] * (double)w_score_reduce[m*128 + c];
        wse[i] = a;
    } else if (i < 12544 + 6272) {      // wre f64 (legacy)
        int t = i - 12544;
        int o = t / 3136;
        int rem = t % 3136;
        int c = rem / 49, r = rem % 49;
        double a = 0.0;
        for (int m = 0; m < 32; ++m)
            a += (double)w_ref[(o*32 + m)*49 + r] * (double)w_ref_reduce[m*64 + c];
        wre[t] = a;
    } else if (i < 12544 + 6272 + 81536) { // wg [3136][26]
        int t = i - 18816;
        int tap = t / 26, o = t % 26;
        wg[t] = (o < 2) ? w_loc[o*3136 + tap] : w_fourier[(o - 2)*3136 + tap];
    } else if (i < 100352 + 768) {      // trig table, bit-identical f32 chain
        int t = i - 100352;             // [cs][k][s]
        int cs = t / 384;
        int k = (t % 384) / 64, s = t % 64;
        const float TWO_PI_F = (float)6.283185307179586;
        float a1 = TWO_PI_F * (float)(k + 1);
        float tf = (float)s * 0.015625f;
        float ang = a1 * tf;
        double av = (double)ang;
        trig[t] = (cs == 0) ? (float)cos(av) : (float)sin(av);
    } else if (i < 101120 + 6272) {     // wre32: [c][ky][2*kx+o] f32
        int t = i - 101120;
        int c = t / 98, r98 = t % 98;
        int ky = r98 / 14, q = r98 % 14;
        int kx = q >> 1, o = q & 1;
        int rr = ky*7 + kx;
        double a = 0.0;
        for (int m = 0; m < 32; ++m)
            a += (double)w_ref[(o*32 + m)*49 + rr] * (double)w_ref_reduce[m*64 + c];
        wre32[t] = (float)a;
    } else if (i < 107392 + 12544) {    // wse32: [c][ky][2*kx+o] f32, c 0..127
        int t = i - 107392;
        int c = t / 98, r98 = t % 98;
        int ky = r98 / 14, q = r98 % 14;
        int kx = q >> 1, o = q & 1;
        int rr = ky*7 + kx;
        double a = 0.0;
        for (int m = 0; m < 64; ++m)
            a += (double)w_score[(o*64 + m)*49 + rr] * (double)w_score_reduce[m*128 + c];
        wse32[t] = (float)a;
    }
}

// ============================================================
// Kernel 2: score conv f32 ranking pass. 512 thr = 2 K-split halves
//   (32 channels each, own LDS patch), combine in LDS. [r10 proven]
// ============================================================
__global__ __launch_bounds__(512) void cpn_score_dense_kernel(
    const float* __restrict__ cf, const float* __restrict__ esf,
    const float* __restrict__ wse32, float2* __restrict__ partial)
{
    __shared__ __align__(16) float spatch[2][1672];    // 2 x 38*44 = 13376 B
    const int tid  = threadIdx.x;
    const int t2   = tid & 255;
    const int h    = tid >> 8;            // wave-uniform K-split half
    const int b    = blockIdx.z >> 1;
    const int srch = blockIdx.z & 1;
    const float* src = srch ? esf : cf;
    const float* sbase = src + ((size_t)(b*64 + h*32) << 16);
    const int row0 = blockIdx.y * 32;
    const int col0 = blockIdx.x * 32;
    const int ty   = t2 >> 3;
    const int txg  = t2 & 7;
    const int cbase = srch*64 + h*32;

    float acc0[4] = {0.f,0.f,0.f,0.f};
    float acc1[4] = {0.f,0.f,0.f,0.f};
    float sreg[6];

    {
        #pragma unroll
        for (int k = 0; k < 6; ++k) {
            int i = k*256 + t2; float v = 0.f;
            if (i < 1520) {
                int r = i/40, j = i%40;
                int gy = row0 - 3 + r, gx = col0 - 4 + j;
                if ((unsigned)gy < 256u && (unsigned)gx < 256u) v = sbase[gy*256 + gx];
            }
            sreg[k] = v;
        }
    }

    for (int c = 0; c < 32; ++c) {
        #pragma unroll
        for (int k = 0; k < 6; ++k) {
            int i = k*256 + t2;
            if (i < 1520) spatch[h][(i/40)*44 + (i%40)] = sreg[k];
        }
        __syncthreads();
        if (c + 1 < 32) {
            const float* sp = sbase + ((size_t)(c+1) << 16);
            #pragma unroll
            for (int k = 0; k < 6; ++k) {
                int i = k*256 + t2; float v = 0.f;
                if (i < 1520) {
                    int r = i/40, j = i%40;
                    int gy = row0 - 3 + r, gx = col0 - 4 + j;
                    if ((unsigned)gy < 256u && (unsigned)gx < 256u) v = sp[gy*256 + gx];
                }
                sreg[k] = v;
            }
        }
        int cg = __builtin_amdgcn_readfirstlane(cbase + c);
        const float* wc = wse32 + cg*98;         // uniform -> scalar loads
        #pragma unroll
        for (int ky = 0; ky < 7; ++ky) {
            const float4* pr4 = reinterpret_cast<const float4*>(&spatch[h][(ty+ky)*44 + txg*4]);
            float4 A = pr4[0], B2 = pr4[1], C2 = pr4[2];
            float rv[12] = {A.x,A.y,A.z,A.w,B2.x,B2.y,B2.z,B2.w,C2.x,C2.y,C2.z,C2.w};
            const float* wp = wc + ky*14;
            float wv[14];
            #pragma unroll
            for (int q = 0; q < 14; ++q) wv[q] = wp[q];
            #pragma unroll
            for (int kx = 0; kx < 7; ++kx) {
                float w0 = wv[2*kx], w1 = wv[2*kx+1];
                #pragma unroll
                for (int p = 0; p < 4; ++p) {
                    float v = rv[p + kx + 1];
                    acc0[p] = fmaf(w0, v, acc0[p]);
                    acc1[p] = fmaf(w1, v, acc1[p]);
                }
            }
        }
        __syncthreads();
    }

    float* cmb = &spatch[0][0];
    if (h == 1) {
        #pragma unroll
        for (int p = 0; p < 4; ++p) { cmb[t2*8 + p] = acc0[p]; cmb[t2*8 + 4 + p] = acc1[p]; }
    }
    __syncthreads();
    if (h == 0) {
        int y = row0 + ty;
        #pragma unroll
        for (int p = 0; p < 4; ++p) {
            float s0 = acc0[p] + cmb[t2*8 + p];
            float s1 = acc1[p] + cmb[t2*8 + 4 + p];
            int x = col0 + txg*4 + p;
            float2 v; v.x = s0; v.y = s1;
            partial[(size_t)(srch*4 + b)*65536 + y*256 + x] = v;
        }
    }
}

// ============================================================
// Kernel 3: d = l1 - l0 (ranking surrogate)
// ============================================================
__global__ __launch_bounds__(256) void cpn_dcomb_kernel(
    const float2* __restrict__ partial, float* __restrict__ d)
{
    int i = blockIdx.x * 256 + threadIdx.x;
    int b = i >> 16, px = i & 65535;
    float2 p0 = partial[(size_t)b*65536 + px];
    float2 p1 = partial[(size_t)(4 + b)*65536 + px];
    float l0 = p0.x + p1.x;
    float l1 = p0.y + p1.y;
    d[i] = l1 - l0;
}

// ============================================================
// Kernel 4: refinement conv f32. 512 thr = 2 K-split halves (32 ch
//   each, own LDS patch), r7-proven inner structure, LDS combine.
//   [r10 proven config, 269 us]
// ============================================================
__global__ __launch_bounds__(512) void cpn_ref_conv_kernel(
    const float* __restrict__ rff, const float* __restrict__ erf,
    const float* __restrict__ wre32, const float* __restrict__ b_ref,
    float* __restrict__ refmap)
{
    __shared__ __align__(16) float4 patches[2][38][19];  // 23104 B
    const int tid = threadIdx.x;
    const int t2  = tid & 255;
    const int h   = tid >> 8;             // wave-uniform
    const int b   = blockIdx.z;
    const int row0 = blockIdx.y * 32;
    const int col0 = blockIdx.x * 64;
    const int tyg = t2 & 31;              // output row
    const int txg = t2 >> 5;              // 8 px each
    const float* sbase = (h ? erf : rff) + ((size_t)(b*32) << 18);

    int   st_r[3], st_f[3];
    long  st_off[3];
    bool  st_ok[3];
    #pragma unroll
    for (int k = 0; k < 3; ++k) {
        int i = k*256 + t2;
        int r = i / 18, f = i % 18;
        int gy = row0 - 3 + r, gx = col0 - 4 + 4*f;
        st_r[k] = r; st_f[k] = f;
        st_ok[k] = (i < 684) && ((unsigned)gy < 512u) && ((unsigned)gx < 509u);
        st_off[k] = (long)gy * 512 + gx;
    }

    float4 s4[3];
    {
        #pragma unroll
        for (int k = 0; k < 3; ++k) {
            float4 v = {0.f,0.f,0.f,0.f};
            if (st_ok[k]) v = *reinterpret_cast<const float4*>(sbase + st_off[k]);
            s4[k] = v;
        }
    }

    float acc0[8] = {0,0,0,0,0,0,0,0};
    float acc1[8] = {0,0,0,0,0,0,0,0};

    for (int c = 0; c < 32; ++c) {
        #pragma unroll
        for (int k = 0; k < 3; ++k) {
            int i = k*256 + t2;
            if (i < 684) patches[h][st_r[k]][st_f[k]] = s4[k];
        }
        __syncthreads();
        if (c + 1 < 32) {
            const float* sp = sbase + ((size_t)(c+1) << 18);
            #pragma unroll
            for (int k = 0; k < 3; ++k) {
                float4 v = {0.f,0.f,0.f,0.f};
                if (st_ok[k]) v = *reinterpret_cast<const float4*>(sp + st_off[k]);
                s4[k] = v;
            }
        }
        int cg = __builtin_amdgcn_readfirstlane(h*32 + c);
        const float* wc = wre32 + cg*98;       // uniform -> scalar loads
        #pragma unroll
        for (int pr = 0; pr < 7; ++pr) {       // pr == ky
            int row = tyg + pr;
            float4 A  = patches[h][row][2*txg + 0];
            float4 B2 = patches[h][row][2*txg + 1];
            float4 C2 = patches[h][row][2*txg + 2];
            float4 D2 = patches[h][row][2*txg + 3];
            float rv[16] = {A.x,A.y,A.z,A.w,B2.x,B2.y,B2.z,B2.w,
                            C2.x,C2.y,C2.z,C2.w,D2.x,D2.y,D2.z,D2.w};
            const float* wp = wc + pr*14;
            float wv[14];
            #pragma unroll
            for (int q = 0; q < 14; ++q) wv[q] = wp[q];
            #pragma unroll
            for (int kx = 0; kx < 7; ++kx) {
                float w0 = wv[2*kx], w1 = wv[2*kx+1];
                #pragma unroll
                for (int p = 0; p < 8; ++p) {
                    float v = rv[p + kx + 1];
                    acc0[p] = fmaf(w0, v, acc0[p]);
                    acc1[p] = fmaf(w1, v, acc1[p]);
                }
            }
        }
        __syncthreads();
    }

    float* cmb = reinterpret_cast<float*>(&patches[0][0][0]);   // 16 KB reuse
    if (h == 1) {
        #pragma unroll
        for (int p = 0; p < 8; ++p) { cmb[t2*16 + p] = acc0[p]; cmb[t2*16 + 8 + p] = acc1[p]; }
    }
    __syncthreads();
    if (h == 0) {
        float br0 = b_ref[0], br1 = b_ref[1];
        int y = row0 + tyg;
        int x0 = col0 + txg*8;
        #pragma unroll
        for (int p = 0; p < 8; ++p) {
            float s0 = acc0[p] + cmb[t2*16 + p];
            float s1 = acc1[p] + cmb[t2*16 + 8 + p];
            refmap[((size_t)(b*2 + 0)*512 + y)*512 + x0 + p] = tanhf(s0 + br0) * 3.0f;
            refmap[((size_t)(b*2 + 1)*512 + y)*512 + x0 + p] = tanhf(s1 + br1) * 3.0f;
        }
    }
}

// ============================================================
// Kernel 5: candidate select, REGISTER-RESIDENT keys (1 global scan).
//   Radix 512th d, margin 0.0625; same counts as r10 (atomics are
//   order-free; clist order canonicalized by sortk).
// ============================================================
__device__ __forceinline__ void cpn_find_bucket(
    unsigned int* hist, unsigned int* seg, int nb, int target, int tid,
    int* s_bsel, int* s_cnt)
{
    int nseg = nb / 32;
    for (int t = tid; t < nseg; t += 1024) {
        unsigned int s = 0;
        for (int q = 0; q < 32; ++q) s += hist[t*32 + q];
        seg[t] = s;
    }
    __syncthreads();
    if (tid == 0) {
        int cum = 0, sg = 0;
        for (int jj = nseg - 1; jj >= 0; --jj) {
            int c = (int)seg[jj];
            if (cum + c >= target) { sg = jj; break; }
            cum += c;
        }
        int bs = sg*32;
        for (int jj = sg*32 + 31; jj >= sg*32; --jj) {
            int c = (int)hist[jj];
            if (cum + c >= target) { bs = jj; break; }
            cum += c;
        }
        *s_bsel = bs; *s_cnt = cum;
    }
    __syncthreads();
}

__device__ __forceinline__ unsigned int cpn_fkey(float v) {
    unsigned int u = __float_as_uint(v);
    return (u & 0x80000000u) ? ~u : (u | 0x80000000u);
}

__global__ __launch_bounds__(1024) void cpn_select_kernel(
    const float* __restrict__ d, int* __restrict__ clist, int* __restrict__ cnt)
{
    const int b = blockIdx.x;
    const int tid = threadIdx.x;
    const float* f = d + (size_t)b * 65536;

    __shared__ unsigned int hist[2048];
    __shared__ unsigned int seg[64];
    __shared__ int s_b, s_c, s_n;

    unsigned int keys[64];                   // register-resident (one scan)
    #pragma unroll
    for (int k = 0; k < 64; ++k) keys[k] = cpn_fkey(f[tid + 1024*k]);

    const int bitsA[3]  = {11,11,10};
    const int shiftA[3] = {21,10,0};

    unsigned int prefix = 0;
    int target = 512;
    for (int pass = 0; pass < 3; ++pass) {
        int sh = shiftA[pass], nb = 1 << bitsA[pass];
        for (int i = tid; i < 2048; i += 1024) hist[i] = 0;
        __syncthreads();
        if (pass == 0) {
            #pragma unroll
            for (int k = 0; k < 64; ++k)
                atomicAdd(&hist[keys[k] >> 21], 1u);
        } else {
            int hs = sh + bitsA[pass];
            #pragma unroll
            for (int k = 0; k < 64; ++k) {
                unsigned int kk = keys[k];
                if ((kk >> hs) == prefix)
                    atomicAdd(&hist[(kk >> sh) & (nb-1)], 1u);
            }
        }
        __syncthreads();
        cpn_find_bucket(hist, seg, nb, target, tid, &s_b, &s_c);
        prefix = (prefix << bitsA[pass]) | (unsigned)s_b;
        target -= s_c;
    }
    float T = (prefix & 0x80000000u) ? __uint_as_float(prefix & 0x7FFFFFFFu)
                                     : __uint_as_float(~prefix);
    unsigned int tkey = cpn_fkey(T - 0.0625f);

    if (tid == 0) s_n = 0;
    __syncthreads();
    #pragma unroll
    for (int k = 0; k < 64; ++k) {
        if (keys[k] >= tkey) {
            int q = atomicAdd(&s_n, 1);
            if (q < 2048) clist[b*2048 + q] = tid + 1024*k;
        }
    }
    __syncthreads();
    if (tid == 0) cnt[b] = (s_n > 2048) ? 2048 : s_n;
}

// ============================================================
// Kernel 6: exact f64 logits at candidates + proven f32 fg chain
// ============================================================
__global__ __launch_bounds__(256) void cpn_recompute_kernel(
    const float* __restrict__ cf, const float* __restrict__ esf,
    const double* __restrict__ wse, const float* __restrict__ b_score,
    const int* __restrict__ clist, const int* __restrict__ cnt,
    uint2* __restrict__ pairs)
{
    const int b = blockIdx.y, q = blockIdx.x, tid = threadIdx.x;
    const int n = cnt[b];
    if (q >= n) {
        if (tid == 0) { uint2 pd; pd.x = 0u; pd.y = 0x7FFFFFFFu; pairs[b*2048 + q] = pd; }
        return;
    }
    const int idx = clist[b*2048 + q];
    const int gy = idx >> 8, gx = idx & 255;

    double L0 = 0.0, L1 = 0.0;
    for (int t = tid; t < 6272; t += 256) {
        int c = t / 49, r = t % 49, ky = r / 7, kx = r % 7;
        int y = gy + ky - 3, x = gx + kx - 3;
        float v = 0.f;
        if ((unsigned)y < 256u && (unsigned)x < 256u) {
            const float* src = (c < 64) ? cf : esf;
            v = src[((size_t)(b*64 + (c & 63)) << 16) + y*256 + x];
        }
        double dv = (double)v;
        L0 = fma(dv, wse[c*49 + r], L0);
        L1 = fma(dv, wse[6272 + c*49 + r], L1);
    }
    #pragma unroll
    for (int off = 32; off; off >>= 1) {
        L0 += __shfl_down(L0, off, 64);
        L1 += __shfl_down(L1, off, 64);
    }
    __shared__ double red[4][2];
    int w = tid >> 6, lane = tid & 63;
    if (lane == 0) { red[w][0] = L0; red[w][1] = L1; }
    __syncthreads();
    if (tid == 0) {
        double S0 = red[0][0] + red[1][0] + red[2][0] + red[3][0];
        double S1 = red[0][1] + red[1][1] + red[2][1] + red[3][1];
        float l0f = (float)(S0 + (double)b_score[0]);
        float l1f = (float)(S1 + (double)b_score[1]);
        float m  = fmaxf(l0f, l1f);
        float e0 = (float)exp((double)(l0f - m));
        float e1 = (float)exp((double)(l1f - m));
        float s  = e0 + e1;
        float lg = (float)log((double)s);
        float ls1 = (l1f - m) - lg;
        float fgv = (float)exp((double)ls1);
        uint2 pr; pr.x = __float_as_uint(fgv); pr.y = (unsigned)idx;
        pairs[b*2048 + q] = pr;
    }
}

// ============================================================
// Kernel 7: per-batch bitonic sort of 2048 (fgbits desc, idx asc)
// ============================================================
__global__ __launch_bounds__(1024) void cpn_sortk_kernel(
    const uint2* __restrict__ pairs, int* __restrict__ tidx,
    float* __restrict__ tscores)
{
    const int b = blockIdx.x;
    const int tid = threadIdx.x;
    __shared__ unsigned int key[2048];
    __shared__ int sidx[2048];

    for (int q = tid; q < 2048; q += 1024) {
        uint2 pr = pairs[b*2048 + q];
        key[q] = pr.x; sidx[q] = (int)pr.y;
    }
    __syncthreads();
    for (int kk = 2; kk <= 2048; kk <<= 1)
        for (int jj = kk >> 1; jj > 0; jj >>= 1) {
            for (int i = tid; i < 2048; i += 1024) {
                int ixj = i ^ jj;
                if (ixj > i) {
                    unsigned int ka = key[i], kc = key[ixj];
                    int ia = sidx[i], ic = sidx[ixj];
                    bool up = ((i & kk) == 0);
                    bool aBefore = (ka > kc) || (ka == kc && ia < ic);
                    if (up ? !aBefore : aBefore) {
                        key[i] = kc; key[ixj] = ka;
                        sidx[i] = ic; sidx[ixj] = ia;
                    }
                }
            }
            __syncthreads();
        }
    for (int q = tid; q < 512; q += 1024) {
        tscores[b*512 + q] = __uint_as_float(key[q]);
        tidx[b*512 + q] = sidx[q];
    }
}

// ============================================================
// Kernel 8 (FUSED): gathered 7x7x64 conv + fourier synthesis +
//   4 refinement iters + boxes, one 256-thread block per point.
//   Numerics identical to r10 (f32 g values via LDS boundary).
// ============================================================
__global__ __launch_bounds__(256) void cpn_gather_contour_kernel(
    const float* __restrict__ cf, const float* __restrict__ wg,
    const float* __restrict__ b_loc, const float* __restrict__ b_fourier,
    const int* __restrict__ tidx, const float* __restrict__ refmap,
    const float* __restrict__ trig,
    float* __restrict__ out_contour, float* __restrict__ out_boxes)
{
    const int b = blockIdx.y, p = blockIdx.x, tid = threadIdx.x;
    const int bp = b*512 + p;
    const int idx = tidx[bp];
    const int gy = idx >> 8, gx = idx & 255;

    double part[26];
    #pragma unroll
    for (int o = 0; o < 26; ++o) part[o] = 0.0;

    for (int t = tid; t < 3136; t += 256) {
        int c = t / 49, rr = t % 49, ky = rr / 7, kx = rr % 7;
        int y = gy + ky - 3, x = gx + kx - 3;
        float v = 0.f;
        if ((unsigned)y < 256u && (unsigned)x < 256u)
            v = cf[((size_t)(b*64 + c)*256 + y)*256 + x];
        const float* wr = wg + t*26;
        double dv = (double)v;
        #pragma unroll
        for (int o = 0; o < 26; ++o) part[o] = fma(dv, (double)wr[o], part[o]);
    }
    #pragma unroll
    for (int o = 0; o < 26; ++o)
        for (int off = 32; off; off >>= 1) part[o] += __shfl_down(part[o], off, 64);

    __shared__ double red[4][26];
    __shared__ float g26[26];
    int w = tid >> 6, lane = tid & 63;
    if (lane == 0) {
        #pragma unroll
        for (int o = 0; o < 26; ++o) red[w][o] = part[o];
    }
    __syncthreads();
    if (tid < 26) {
        double s = red[0][tid] + red[1][tid] + red[2][tid] + red[3][tid];
        s += (tid < 2) ? (double)b_loc[tid] : (double)b_fourier[tid - 2];
        g26[tid] = (float)s;                 // f32 layer boundary (as r10)
    }
    __syncthreads();

    if (tid < 64) {
        const int s = tid;
        const float* g = g26;
        float cx = ((float)gx + g[0]) * 2.0f;
        float cy = ((float)gy + g[1]) * 2.0f;

        float sxc = 0.f, sxs = 0.f, syc = 0.f, sys = 0.f;
        #pragma unroll
        for (int k = 0; k < 6; ++k) {
            float cs = trig[k*64 + s];
            float sn = trig[384 + k*64 + s];
            float t0 = g[2 + k*4 + 0] * cs; asm volatile("" : "+v"(t0)); sxc += t0;
            float t1 = g[2 + k*4 + 1] * sn; asm volatile("" : "+v"(t1)); sxs += t1;
            float t2 = g[2 + k*4 + 2] * cs; asm volatile("" : "+v"(t2)); syc += t2;
            float t3 = g[2 + k*4 + 3] * sn; asm volatile("" : "+v"(t3)); sys += t3;
        }
        float px = sxc + sxs;
        float py = syc + sys;
        float x = px * 2.0f; asm volatile("" : "+v"(x)); x += cx;
        float y = py * 2.0f; asm volatile("" : "+v"(y)); y += cy;

        const float* r0 = refmap + (size_t)b * 2 * 262144;
        const float* r1 = r0 + 262144;
        #pragma unroll
        for (int it = 0; it < 4; ++it) {
            float xr = rintf(x); xr = fminf(fmaxf(xr, 0.f), 511.f);
            float yr = rintf(y); yr = fminf(fmaxf(yr, 0.f), 511.f);
            int xi = (int)xr, yi = (int)yr;
            x += r0[yi*512 + xi];
            y += r1[yi*512 + xi];
        }

        out_contour[((size_t)bp*64 + s)*2 + 0] = x;
        out_contour[((size_t)bp*64 + s)*2 + 1] = y;

        float mnx = x, mxx = x, mny = y, mxy = y;
        #pragma unroll
        for (int off = 32; off; off >>= 1) {
            mnx = fminf(mnx, __shfl_xor(mnx, off, 64));
            mny = fminf(mny, __shfl_xor(mny, off, 64));
            mxx = fmaxf(mxx, __shfl_xor(mxx, off, 64));
            mxy = fmaxf(mxy, __shfl_xor(mxy, off, 64));
        }
        if (s == 0) {
            out_boxes[bp*4 + 0] = mnx;
            out_boxes[bp*4 + 1] = mny;
            out_boxes[bp*4 + 2] = mxx;
            out_boxes[bp*4 + 3] = mxy;
        }
    }
}

// ============================================================
// Kernel 9: sequential NMS, literal f32 op order [r10 original]
// ============================================================
__global__ __launch_bounds__(512) void cpn_nms_kernel(
    const float* __restrict__ boxes, const float* __restrict__ scores,
    float* __restrict__ keep_out)
{
    const int b = blockIdx.x;
    const int j = threadIdx.x;
    __shared__ float X1[512], Y1[512], X2[512], Y2[512], AR[512];
    __shared__ int keep[512];

    const float* bb = boxes + b*512*4;
    float x1 = bb[j*4+0], y1 = bb[j*4+1], x2 = bb[j*4+2], y2 = bb[j*4+3];
    float aj = fmaxf(x2 - x1, 0.f) * fmaxf(y2 - y1, 0.f);
    X1[j] = x1; Y1[j] = y1; X2[j] = x2; Y2[j] = y2; AR[j] = aj;
    keep[j] = (scores[b*512 + j] > 0.5f) ? 1 : 0;
    __syncthreads();

    for (int i = 0; i < 512; ++i) {
        if (keep[i] && j > i) {
            float ix1 = fmaxf(x1, X1[i]);
            float iy1 = fmaxf(y1, Y1[i]);
            float ix2 = fminf(x2, X2[i]);
            float iy2 = fminf(y2, Y2[i]);
            float inter = fmaxf(ix2 - ix1, 0.f) * fmaxf(iy2 - iy1, 0.f);
            float uni = (aj + AR[i]) - inter;
            float iou = inter / fmaxf(uni, 1e-8f);
            if (iou > 0.2f) keep[j] = 0;
        }
        __syncthreads();
    }
    keep_out[b*512 + j] = keep[j] ? 1.0f : 0.0f;
}

// ============================================================
extern "C" void kernel_launch(void* const* d_in, const int* in_sizes, int n_in,
                              void* d_out, int out_size, void* d_ws, size_t ws_size,
                              hipStream_t stream)
{
    if (ws_size < WS_END) return;

    const float* cf   = (const float*)d_in[0];
    const float* esf  = (const float*)d_in[1];
    const float* rff  = (const float*)d_in[2];
    const float* erf  = (const float*)d_in[3];
    const float* w_sr = (const float*)d_in[4];
    const float* w_s  = (const float*)d_in[5];
    const float* b_s  = (const float*)d_in[6];
    const float* w_l  = (const float*)d_in[7];
    const float* b_l  = (const float*)d_in[8];
    const float* w_f  = (const float*)d_in[9];
    const float* b_f  = (const float*)d_in[10];
    const float* w_rr = (const float*)d_in[11];
    const float* w_r  = (const float*)d_in[12];
    const float* b_r  = (const float*)d_in[13];

    char* ws = (char*)d_ws;
    float*  dbuf = (float*)(ws + WS_D);
    float*  refm = (float*)(ws + WS_REF);
    float2* spart = (float2*)(ws + WS_SPART);
    double* wse  = (double*)(ws + WS_WSE);
    double* wre  = (double*)(ws + WS_WRE);
    float*  wg   = (float*)(ws + WS_WG);
    int*    tidx = (int*)(ws + WS_TIDX);
    float*  trig = (float*)(ws + WS_TRIG);
    int*    clist = (int*)(ws + WS_CLIST);
    int*    cnt  = (int*)(ws + WS_CNT);
    uint2*  pairs = (uint2*)(ws + WS_PAIRS);
    float*  wre32 = (float*)(ws + WS_WRE32);
    float*  wse32 = (float*)(ws + WS_WSE32);

    float* out_contour = (float*)d_out;                  // 4*512*64*2
    float* out_scores  = out_contour + 262144;           // 4*512
    float* out_keep    = out_scores + 2048;              // 4*512
    float* out_boxes   = out_keep + 2048;                // 4*512*4

    cpn_prep_kernel<<<dim3(469), dim3(256), 0, stream>>>(
        w_sr, w_s, w_l, w_f, w_rr, w_r, wse, wre, wg, trig, wre32, wse32);
    cpn_score_dense_kernel<<<dim3(8, 8, 8), dim3(512), 0, stream>>>(
        cf, esf, wse32, spart);
    cpn_ref_conv_kernel<<<dim3(8, 16, 4), dim3(512), 0, stream>>>(
        rff, erf, wre32, b_r, refm);
    cpn_dcomb_kernel<<<dim3(1024), dim3(256), 0, stream>>>(spart, dbuf);
    cpn_select_kernel<<<dim3(4), dim3(1024), 0, stream>>>(dbuf, clist, cnt);
    cpn_recompute_kernel<<<dim3(2048, 4), dim3(256), 0, stream>>>(
        cf, esf, wse, b_s, clist, cnt, pairs);
    cpn_sortk_kernel<<<dim3(4), dim3(1024), 0, stream>>>(pairs, tidx, out_scores);
    cpn_gather_contour_kernel<<<dim3(512, 4), dim3(256), 0, stream>>>(
        cf, wg, b_l, b_f, tidx, refm, trig, out_contour, out_boxes);
    cpn_nms_kernel<<<dim3(4), dim3(512), 0, stream>>>(
        out_boxes, out_scores, out_keep);
}